// Round 1
// baseline (11052.951 us; speedup 1.0000x reference)
//
#include <hip/hip_runtime.h>

#define THREADS 256

__device__ __forceinline__ float fast_tanh(float xx) {
    // tanh(x) = 1 - 2/(1 + exp(2x)); robust at +-inf, ~1e-7 abs err
    float e = __expf(2.0f * xx);
    return 1.0f - 2.0f * __builtin_amdgcn_rcpf(1.0f + e);
}

__global__ __launch_bounds__(THREADS) void edge_mlp_kernel(
    const float* __restrict__ x,
    const int*   __restrict__ ei,
    const float* __restrict__ W1, const float* __restrict__ b1,
    const float* __restrict__ g1, const float* __restrict__ bt1,
    const float* __restrict__ W2, const float* __restrict__ b2,
    const float* __restrict__ g2, const float* __restrict__ bt2,
    const float* __restrict__ W3, const float* __restrict__ b3,
    const float* __restrict__ g3, const float* __restrict__ bt3,
    const float* __restrict__ W4, const float* __restrict__ b4,
    float* __restrict__ out, int nEdges)
{
    // per-thread private row in LDS for dynamic-k reads of h1/h2.
    // stride 65 floats: 65 % 32 == 1 -> lanes map to distinct-ish banks (2-way, free)
    __shared__ float hbuf[THREADS * 65];

    const int tid = threadIdx.x;
    const int e = blockIdx.x * THREADS + tid;
    if (e >= nEdges) return;

    const int srcn = ei[e];
    const int dstn = ei[nEdges + e];

    float acc[64];
    #pragma unroll
    for (int j = 0; j < 64; ++j) acc[j] = b1[j];

    // ---------------- Layer 1: [2*64] @ W1[128][64] ----------------
    #pragma unroll 1
    for (int half = 0; half < 2; ++half) {
        const float4* row = reinterpret_cast<const float4*>(
            x + (size_t)(half ? dstn : srcn) * 64);
        const float* Wb = W1 + half * 64 * 64;
        #pragma unroll 1
        for (int c = 0; c < 8; ++c) {          // 8 k-values per chunk
            float4 u0 = row[c * 2 + 0];
            float4 u1 = row[c * 2 + 1];
            float hk[8] = {u0.x, u0.y, u0.z, u0.w, u1.x, u1.y, u1.z, u1.w};
            #pragma unroll
            for (int kk = 0; kk < 8; ++kk) {
                const float* wr = Wb + (c * 8 + kk) * 64;   // uniform -> s_load
                #pragma unroll
                for (int j = 0; j < 64; ++j)
                    acc[j] = fmaf(hk[kk], wr[j], acc[j]);
            }
        }
    }

    // ---------------- helpers ----------------
    auto ln_tanh = [&](const float* g, const float* bt) {
        float s0 = 0.f, s1 = 0.f, s2 = 0.f, s3 = 0.f;
        float q0 = 0.f, q1 = 0.f, q2 = 0.f, q3 = 0.f;
        #pragma unroll
        for (int j = 0; j < 64; j += 4) {
            s0 += acc[j];     s1 += acc[j + 1];
            s2 += acc[j + 2]; s3 += acc[j + 3];
            q0 = fmaf(acc[j],     acc[j],     q0);
            q1 = fmaf(acc[j + 1], acc[j + 1], q1);
            q2 = fmaf(acc[j + 2], acc[j + 2], q2);
            q3 = fmaf(acc[j + 3], acc[j + 3], q3);
        }
        const float mean = ((s0 + s1) + (s2 + s3)) * 0.015625f;
        float var = ((q0 + q1) + (q2 + q3)) * 0.015625f - mean * mean;
        var = fmaxf(var, 0.0f);
        const float rstd = __builtin_amdgcn_rsqf(var + 1e-5f);
        #pragma unroll
        for (int j = 0; j < 64; ++j) {
            float v = (acc[j] - mean) * rstd;
            acc[j] = fast_tanh(fmaf(v, g[j], bt[j]));
        }
    };

    float* hrow = hbuf + tid * 65;
    auto dense_from_lds = [&](const float* W, const float* b) {
        // stash inputs (currently in acc) into this thread's LDS row
        #pragma unroll
        for (int j = 0; j < 64; ++j) hrow[j] = acc[j];
        #pragma unroll
        for (int j = 0; j < 64; ++j) acc[j] = b[j];
        #pragma unroll 4
        for (int k = 0; k < 64; ++k) {
            float hk = hrow[k];
            const float* wr = W + k * 64;      // uniform -> s_load
            #pragma unroll
            for (int j = 0; j < 64; ++j)
                acc[j] = fmaf(hk, wr[j], acc[j]);
        }
    };

    // ---------------- Layers 2..4 ----------------
    ln_tanh(g1, bt1);
    dense_from_lds(W2, b2);
    ln_tanh(g2, bt2);
    dense_from_lds(W3, b3);
    ln_tanh(g3, bt3);

    float o = b4[0];
    #pragma unroll
    for (int j = 0; j < 64; ++j) o = fmaf(acc[j], W4[j], o);

    out[e] = __builtin_amdgcn_rcpf(1.0f + __expf(-o));   // sigmoid
}

extern "C" void kernel_launch(void* const* d_in, const int* in_sizes, int n_in,
                              void* d_out, int out_size, void* d_ws, size_t ws_size,
                              hipStream_t stream) {
    const float* x   = (const float*)d_in[0];
    const int*   ei  = (const int*)  d_in[1];
    const float* W1  = (const float*)d_in[2];
    const float* b1  = (const float*)d_in[3];
    const float* g1  = (const float*)d_in[4];
    const float* bt1 = (const float*)d_in[5];
    const float* W2  = (const float*)d_in[6];
    const float* b2  = (const float*)d_in[7];
    const float* g2  = (const float*)d_in[8];
    const float* bt2 = (const float*)d_in[9];
    const float* W3  = (const float*)d_in[10];
    const float* b3  = (const float*)d_in[11];
    const float* g3  = (const float*)d_in[12];
    const float* bt3 = (const float*)d_in[13];
    const float* W4  = (const float*)d_in[14];
    const float* b4  = (const float*)d_in[15];
    float* out = (float*)d_out;

    const int nEdges = in_sizes[1] / 2;
    const int grid = (nEdges + THREADS - 1) / THREADS;
    hipLaunchKernelGGL(edge_mlp_kernel, dim3(grid), dim3(THREADS), 0, stream,
                       x, ei, W1, b1, g1, bt1, W2, b2, g2, bt2,
                       W3, b3, g3, bt3, W4, b4, out, nEdges);
}

// Round 2
// 174.710 us; speedup vs baseline: 63.2644x; 63.2644x over previous
//
#include <hip/hip_runtime.h>

#define BLOCK 512   // 8 waves
#define GRID  512

typedef __attribute__((ext_vector_type(8))) short short8;   // 8 x bf16 (4 VGPRs)
typedef __attribute__((ext_vector_type(4))) float f32x4;    // MFMA C/D frag

__device__ __forceinline__ unsigned short f2bf(float f) {
    // f32 -> bf16 round-to-nearest-even (inputs are finite; no NaN handling)
    unsigned u = __builtin_bit_cast(unsigned, f);
    u += 0x7FFFu + ((u >> 16) & 1u);
    return (unsigned short)(u >> 16);
}

__device__ __forceinline__ float fast_tanh(float v) {
    // tanh(v) = 1 - 2/(1+exp(2v)); robust at +-inf
    float e = __expf(2.0f * v);
    return 1.0f - 2.0f * __builtin_amdgcn_rcpf(1.0f + e);
}

// ---- LayerNorm (bias -> mean/var over 64 cols -> affine -> tanh), in place on A ----
// A[nf][i] holds C(row = kg*4+i, col = nf*16+cl). Row stats reduce across the 16
// cl-lanes of the group via shfl_xor(1,2,4,8).
#define LN_TANH(L, A)                                                         \
    {                                                                         \
        float s_[4], q_[4];                                                   \
        _Pragma("unroll")                                                     \
        for (int i = 0; i < 4; ++i) {                                         \
            float a0 = A[0][i] + bR[L][0];                                    \
            float a1 = A[1][i] + bR[L][1];                                    \
            float a2 = A[2][i] + bR[L][2];                                    \
            float a3 = A[3][i] + bR[L][3];                                    \
            A[0][i] = a0; A[1][i] = a1; A[2][i] = a2; A[3][i] = a3;           \
            s_[i] = (a0 + a1) + (a2 + a3);                                    \
            q_[i] = fmaf(a3, a3, fmaf(a2, a2, fmaf(a1, a1, a0 * a0)));        \
        }                                                                     \
        _Pragma("unroll")                                                     \
        for (int m_ = 1; m_ < 16; m_ <<= 1) {                                 \
            _Pragma("unroll")                                                 \
            for (int i = 0; i < 4; ++i) {                                     \
                s_[i] += __shfl_xor(s_[i], m_);                               \
                q_[i] += __shfl_xor(q_[i], m_);                               \
            }                                                                 \
        }                                                                     \
        _Pragma("unroll")                                                     \
        for (int i = 0; i < 4; ++i) {                                         \
            const float mu = s_[i] * 0.015625f;                               \
            float var = fmaf(q_[i], 0.015625f, -mu * mu);                     \
            var = fmaxf(var, 0.0f);                                           \
            const float rs = __builtin_amdgcn_rsqf(var + 1e-5f);              \
            const float mrs = mu * rs;                                        \
            _Pragma("unroll")                                                 \
            for (int nf = 0; nf < 4; ++nf) {                                  \
                float vv = fmaf(A[nf][i], rs, -mrs);                          \
                A[nf][i] = fast_tanh(fmaf(vv, gR[L][nf], btR[L][nf]));        \
            }                                                                 \
        }                                                                     \
    }

// scatter h (bf16) to this wave's LDS tile, row-major [16][72] halfwords
#define H_STORE(A)                                                            \
    _Pragma("unroll")                                                         \
    for (int nf = 0; nf < 4; ++nf) {                                          \
        _Pragma("unroll")                                                     \
        for (int i = 0; i < 4; ++i)                                           \
            hwv[(kg * 4 + i) * 72 + nf * 16 + cl] = f2bf(A[nf][i]);           \
    }

__global__ __launch_bounds__(BLOCK, 1) void edge_mlp_mfma(
    const float* __restrict__ x, const int* __restrict__ ei,
    const float* __restrict__ W1, const float* __restrict__ b1,
    const float* __restrict__ g1, const float* __restrict__ bt1,
    const float* __restrict__ W2, const float* __restrict__ b2,
    const float* __restrict__ g2, const float* __restrict__ bt2,
    const float* __restrict__ W3, const float* __restrict__ b3,
    const float* __restrict__ g3, const float* __restrict__ bt3,
    const float* __restrict__ W4, const float* __restrict__ b4,
    float* __restrict__ out, int E)
{
    // 32 weight fragments (W1:16, W2:8, W3:8), each 64 lanes x 16B = 1 KiB
    __shared__ unsigned short wlds[32 * 512];
    // per-wave h tile: 16 rows x 72 halfwords (bf16), 2.25 KiB each
    __shared__ unsigned short hlds[8 * 16 * 72];

    const int tid  = threadIdx.x;
    const int widx = tid >> 6;
    const int lane = tid & 63;
    const int kg   = lane >> 4;   // 0..3
    const int cl   = lane & 15;   // 0..15

    // ---------- stage weights as bf16 B-fragments (once per block) ----------
    // B-frag(kb,nf): lane holds W[kb*32 + kg*8 + j][nf*16 + cl], j=0..7
    for (int fi = widx; fi < 32; fi += 8) {
        const float* Wsrc; int fk;
        if (fi < 16)      { Wsrc = W1; fk = fi;      }
        else if (fi < 24) { Wsrc = W2; fk = fi - 16; }
        else              { Wsrc = W3; fk = fi - 24; }
        const int kb = fk >> 2, nf = fk & 3;
        const float* src = Wsrc + (kb * 32 + kg * 8) * 64 + nf * 16 + cl;
        short8 pk;
        #pragma unroll
        for (int j = 0; j < 8; ++j) pk[j] = (short)f2bf(src[j * 64]);
        *reinterpret_cast<short8*>(&wlds[fi * 512 + lane * 8]) = pk;
    }

    // ---------- per-lane epilogue params: col = nf*16 + cl ----------
    float bR[3][4], gR[3][4], btR[3][4], w4R[4];
    #pragma unroll
    for (int nf = 0; nf < 4; ++nf) {
        const int c = nf * 16 + cl;
        bR[0][nf] = b1[c];  gR[0][nf] = g1[c];  btR[0][nf] = bt1[c];
        bR[1][nf] = b2[c];  gR[1][nf] = g2[c];  btR[1][nf] = bt2[c];
        bR[2][nf] = b3[c];  gR[2][nf] = g3[c];  btR[2][nf] = bt3[c];
        w4R[nf] = W4[c];
    }
    const float b4s = b4[0];

    __syncthreads();

    unsigned short* hwv = &hlds[widx * (16 * 72)];
    const int hrd = cl * 72;   // A-frag read: row = cl for this lane

    const int ntiles = (E + 15) >> 4;
    const int nwaves = (int)gridDim.x * 8;

    for (int t = (int)blockIdx.x * 8 + widx; t < ntiles; t += nwaves) {
        const int e0 = t << 4;
        const int er = min(e0 + cl, E - 1);
        const int ns = ei[er];         // start node for edge row cl
        const int ne = ei[E + er];     // end node

        // ---------------- Layer 1: gather + [16x128]@[128x64] ----------------
        f32x4 acc[4] = {{0,0,0,0},{0,0,0,0},{0,0,0,0},{0,0,0,0}};
        #pragma unroll
        for (int kb = 0; kb < 4; ++kb) {
            const float* xp = x + (size_t)(kb < 2 ? ns : ne) * 64
                              + (kb & 1) * 32 + kg * 8;
            const float4 u0 = *reinterpret_cast<const float4*>(xp);
            const float4 u1 = *reinterpret_cast<const float4*>(xp + 4);
            short8 af;
            af[0] = (short)f2bf(u0.x); af[1] = (short)f2bf(u0.y);
            af[2] = (short)f2bf(u0.z); af[3] = (short)f2bf(u0.w);
            af[4] = (short)f2bf(u1.x); af[5] = (short)f2bf(u1.y);
            af[6] = (short)f2bf(u1.z); af[7] = (short)f2bf(u1.w);
            #pragma unroll
            for (int nf = 0; nf < 4; ++nf) {
                const short8 bf = *reinterpret_cast<const short8*>(
                    &wlds[(kb * 4 + nf) * 512 + lane * 8]);
                acc[nf] = __builtin_amdgcn_mfma_f32_16x16x32_bf16(af, bf, acc[nf], 0, 0, 0);
            }
        }
        LN_TANH(0, acc);
        H_STORE(acc);

        // ---------------- Layer 2 ----------------
        f32x4 acc2[4] = {{0,0,0,0},{0,0,0,0},{0,0,0,0},{0,0,0,0}};
        #pragma unroll
        for (int kb = 0; kb < 2; ++kb) {
            const short8 af = *reinterpret_cast<const short8*>(
                &hwv[hrd + kb * 32 + kg * 8]);
            #pragma unroll
            for (int nf = 0; nf < 4; ++nf) {
                const short8 bf = *reinterpret_cast<const short8*>(
                    &wlds[(16 + kb * 4 + nf) * 512 + lane * 8]);
                acc2[nf] = __builtin_amdgcn_mfma_f32_16x16x32_bf16(af, bf, acc2[nf], 0, 0, 0);
            }
        }
        LN_TANH(1, acc2);
        H_STORE(acc2);

        // ---------------- Layer 3 ----------------
        f32x4 acc3[4] = {{0,0,0,0},{0,0,0,0},{0,0,0,0},{0,0,0,0}};
        #pragma unroll
        for (int kb = 0; kb < 2; ++kb) {
            const short8 af = *reinterpret_cast<const short8*>(
                &hwv[hrd + kb * 32 + kg * 8]);
            #pragma unroll
            for (int nf = 0; nf < 4; ++nf) {
                const short8 bf = *reinterpret_cast<const short8*>(
                    &wlds[(24 + kb * 4 + nf) * 512 + lane * 8]);
                acc3[nf] = __builtin_amdgcn_mfma_f32_16x16x32_bf16(af, bf, acc3[nf], 0, 0, 0);
            }
        }
        LN_TANH(2, acc3);

        // ---------------- Layer 4: dot(64) + sigmoid ----------------
        float p[4];
        #pragma unroll
        for (int i = 0; i < 4; ++i)
            p[i] = fmaf(acc3[3][i], w4R[3], fmaf(acc3[2][i], w4R[2],
                   fmaf(acc3[1][i], w4R[1], acc3[0][i] * w4R[0])));
        #pragma unroll
        for (int m_ = 1; m_ < 16; m_ <<= 1) {
            #pragma unroll
            for (int i = 0; i < 4; ++i) p[i] += __shfl_xor(p[i], m_);
        }
        if (cl == 0) {
            #pragma unroll
            for (int i = 0; i < 4; ++i) {
                const int e = e0 + kg * 4 + i;
                if (e < E) {
                    const float o = p[i] + b4s;
                    out[e] = __builtin_amdgcn_rcpf(1.0f + __expf(-o));
                }
            }
        }
    }
}

extern "C" void kernel_launch(void* const* d_in, const int* in_sizes, int n_in,
                              void* d_out, int out_size, void* d_ws, size_t ws_size,
                              hipStream_t stream) {
    const float* x   = (const float*)d_in[0];
    const int*   ei  = (const int*)  d_in[1];
    const float* W1  = (const float*)d_in[2];
    const float* b1  = (const float*)d_in[3];
    const float* g1  = (const float*)d_in[4];
    const float* bt1 = (const float*)d_in[5];
    const float* W2  = (const float*)d_in[6];
    const float* b2  = (const float*)d_in[7];
    const float* g2  = (const float*)d_in[8];
    const float* bt2 = (const float*)d_in[9];
    const float* W3  = (const float*)d_in[10];
    const float* b3  = (const float*)d_in[11];
    const float* g3  = (const float*)d_in[12];
    const float* bt3 = (const float*)d_in[13];
    const float* W4  = (const float*)d_in[14];
    const float* b4  = (const float*)d_in[15];
    float* out = (float*)d_out;

    const int E = in_sizes[1] / 2;
    hipLaunchKernelGGL(edge_mlp_mfma, dim3(GRID), dim3(BLOCK), 0, stream,
                       x, ei, W1, b1, g1, bt1, W2, b2, g2, bt2,
                       W3, b3, g3, bt3, W4, b4, out, E);
}

// Round 4
// 124.062 us; speedup vs baseline: 89.0920x; 1.4082x over previous
//
#include <hip/hip_runtime.h>

#define BLOCK 512   // 8 waves
#define GRID  512   // 2 blocks/CU, grid-stride over tiles

typedef __attribute__((ext_vector_type(8))) short short8;   // 8 x bf16
typedef __attribute__((ext_vector_type(4))) float f32x4;    // MFMA C/D frag

__device__ __forceinline__ unsigned short f2bf(float f) {
    unsigned u = __builtin_bit_cast(unsigned, f);
    u += 0x7FFFu + ((u >> 16) & 1u);
    return (unsigned short)(u >> 16);
}

__device__ __forceinline__ unsigned pkbf(float lo, float hi) {
    // dst[15:0]=bf16(lo), dst[31:16]=bf16(hi), RNE
    unsigned r;
    asm("v_cvt_pk_bf16_f32 %0, %1, %2" : "=v"(r) : "v"(lo), "v"(hi));
    return r;
}

__device__ __forceinline__ float fast_tanh(float v) {
    float e = __expf(2.0f * v);
    return 1.0f - 2.0f * __builtin_amdgcn_rcpf(1.0f + e);
}

// LayerNorm + tanh, transposed layout: lane holds edge `cl`, h-cols m*16+kg*4+i.
// Stats: in-lane 16-sum, then xor-reduce over the 4 kg groups (masks 16,32).
#define LN_T(PB, PG, PT, A)                                                   \
    {                                                                         \
        float s = 0.f, q = 0.f;                                               \
        _Pragma("unroll")                                                     \
        for (int m = 0; m < 4; ++m) {                                         \
            const float4 pb = *reinterpret_cast<const float4*>(               \
                plds + (PB) * 64 + m * 16 + kg * 4);                          \
            A[m][0] += pb.x; A[m][1] += pb.y;                                 \
            A[m][2] += pb.z; A[m][3] += pb.w;                                 \
            s += (A[m][0] + A[m][1]) + (A[m][2] + A[m][3]);                   \
            q = fmaf(A[m][0], A[m][0], q); q = fmaf(A[m][1], A[m][1], q);     \
            q = fmaf(A[m][2], A[m][2], q); q = fmaf(A[m][3], A[m][3], q);     \
        }                                                                     \
        s += __shfl_xor(s, 16); s += __shfl_xor(s, 32);                       \
        q += __shfl_xor(q, 16); q += __shfl_xor(q, 32);                       \
        const float mu = s * 0.015625f;                                       \
        float var = fmaf(q, 0.015625f, -mu * mu);                             \
        var = fmaxf(var, 0.0f);                                               \
        const float rs = __builtin_amdgcn_rsqf(var + 1e-5f);                  \
        const float mrs = mu * rs;                                            \
        _Pragma("unroll")                                                     \
        for (int m = 0; m < 4; ++m) {                                         \
            const float4 pg = *reinterpret_cast<const float4*>(               \
                plds + (PG) * 64 + m * 16 + kg * 4);                          \
            const float4 pt = *reinterpret_cast<const float4*>(               \
                plds + (PT) * 64 + m * 16 + kg * 4);                          \
            A[m][0] = fast_tanh(fmaf(fmaf(A[m][0], rs, -mrs), pg.x, pt.x));   \
            A[m][1] = fast_tanh(fmaf(fmaf(A[m][1], rs, -mrs), pg.y, pt.y));   \
            A[m][2] = fast_tanh(fmaf(fmaf(A[m][2], rs, -mrs), pg.z, pt.z));   \
            A[m][3] = fast_tanh(fmaf(fmaf(A[m][3], rs, -mrs), pg.w, pt.w));   \
        }                                                                     \
    }

// store 16 bf16 (4 contiguous cols per m) to this wave's h tile: 4x ds_write_b64
#define H_STORE_T(A)                                                          \
    _Pragma("unroll")                                                         \
    for (int m = 0; m < 4; ++m) {                                             \
        uint2 u;                                                              \
        u.x = pkbf(A[m][0], A[m][1]);                                         \
        u.y = pkbf(A[m][2], A[m][3]);                                         \
        *reinterpret_cast<uint2*>(hwv + cl * 72 + m * 16 + kg * 4) = u;       \
    }

template<bool PREBF>
__global__ __launch_bounds__(BLOCK, 1) void edge_mlp_t(
    const void* __restrict__ xsrc, const int* __restrict__ ei,
    const float* __restrict__ W1, const float* __restrict__ b1,
    const float* __restrict__ g1, const float* __restrict__ bt1,
    const float* __restrict__ W2, const float* __restrict__ b2,
    const float* __restrict__ g2, const float* __restrict__ bt2,
    const float* __restrict__ W3, const float* __restrict__ b3,
    const float* __restrict__ g3, const float* __restrict__ bt3,
    const float* __restrict__ W4, const float* __restrict__ b4,
    float* __restrict__ out, int E)
{
    // Wt frags: fi<16 -> L1 (m=fi>>2, kb=fi&3); 16..23 -> L2; 24..31 -> L3.
    // frag(fi): lane holds W[kb*32 + kg*8 + j][m*16 + cl], j=0..7 (A-operand = W^T)
    __shared__ unsigned short wlds[32 * 512];          // 32 KiB
    __shared__ unsigned short hlds[8 * 16 * 72];       // per-wave [16 edge][72] bf16
    __shared__ float plds[10 * 64];                    // b1,g1,bt1,b2,g2,bt2,b3,g3,bt3,W4

    const int tid  = threadIdx.x;
    const int widx = tid >> 6;
    const int lane = tid & 63;
    const int kg   = lane >> 4;   // 0..3
    const int cl   = lane & 15;   // 0..15 = this lane's edge within tile

    for (int fi = widx; fi < 32; fi += 8) {
        const float* Wsrc; int m, kb;
        if (fi < 16) { Wsrc = W1; m = fi >> 2; kb = fi & 3; }
        else { int f = fi - 16; Wsrc = (f < 8) ? W2 : W3; f &= 7; m = f >> 1; kb = f & 1; }
        const float* src = Wsrc + (size_t)(kb * 32 + kg * 8) * 64 + m * 16 + cl;
        short8 pk8;
        #pragma unroll
        for (int j = 0; j < 8; ++j) pk8[j] = (short)f2bf(src[j * 64]);
        *reinterpret_cast<short8*>(&wlds[fi * 512 + lane * 8]) = pk8;
    }
    // params -> LDS (10 vectors of 64). NOTE: grid-stride — BLOCK(512) < 640;
    // Round-3 bug was `if (tid < 640)` leaving bt3/W4 unstaged.
    for (int i = tid; i < 640; i += BLOCK) {
        const int p = i >> 6, c = i & 63;
        const float* sp;
        switch (p) {
            case 0: sp = b1;  break; case 1: sp = g1;  break; case 2: sp = bt1; break;
            case 3: sp = b2;  break; case 4: sp = g2;  break; case 5: sp = bt2; break;
            case 6: sp = b3;  break; case 7: sp = g3;  break; case 8: sp = bt3; break;
            default: sp = W4; break;
        }
        plds[i] = sp[c];
    }
    const float b4s = b4[0];
    __syncthreads();

    const unsigned short* xb = (const unsigned short*)xsrc;
    const float*          xf = (const float*)xsrc;
    unsigned short* hwv = hlds + widx * (16 * 72);

    const int ntiles = (E + 15) >> 4;
    const int nwaves = GRID * 8;

    for (int t = (int)blockIdx.x * 8 + widx; t < ntiles; t += nwaves) {
        const int e0 = t << 4;
        const int er = min(e0 + cl, E - 1);
        const int ns = ei[er];
        const int ne = ei[E + er];

        // ---------- Layer 1: gather B-frags (8 contiguous feats of edge cl) ----------
        short8 xa[4];
        #pragma unroll
        for (int kb = 0; kb < 4; ++kb) {
            const size_t off = (size_t)(kb < 2 ? ns : ne) * 64 + (kb & 1) * 32 + kg * 8;
            if constexpr (PREBF) {
                xa[kb] = *reinterpret_cast<const short8*>(xb + off);
            } else {
                const float4 u0 = *reinterpret_cast<const float4*>(xf + off);
                const float4 u1 = *reinterpret_cast<const float4*>(xf + off + 4);
                uint4 tpk;
                tpk.x = pkbf(u0.x, u0.y); tpk.y = pkbf(u0.z, u0.w);
                tpk.z = pkbf(u1.x, u1.y); tpk.w = pkbf(u1.z, u1.w);
                xa[kb] = __builtin_bit_cast(short8, tpk);
            }
        }

        f32x4 acc[4] = {{0,0,0,0},{0,0,0,0},{0,0,0,0},{0,0,0,0}};
        #pragma unroll
        for (int kb = 0; kb < 4; ++kb) {
            #pragma unroll
            for (int m = 0; m < 4; ++m) {
                const short8 wf = *reinterpret_cast<const short8*>(
                    &wlds[(m * 4 + kb) * 512 + lane * 8]);
                acc[m] = __builtin_amdgcn_mfma_f32_16x16x32_bf16(wf, xa[kb], acc[m], 0, 0, 0);
            }
        }
        LN_T(0, 1, 2, acc);
        H_STORE_T(acc);

        // ---------- Layer 2 ----------
        f32x4 acc2[4] = {{0,0,0,0},{0,0,0,0},{0,0,0,0},{0,0,0,0}};
        #pragma unroll
        for (int kb = 0; kb < 2; ++kb) {
            const short8 hf = *reinterpret_cast<const short8*>(
                hwv + cl * 72 + kb * 32 + kg * 8);
            #pragma unroll
            for (int m = 0; m < 4; ++m) {
                const short8 wf = *reinterpret_cast<const short8*>(
                    &wlds[(16 + m * 2 + kb) * 512 + lane * 8]);
                acc2[m] = __builtin_amdgcn_mfma_f32_16x16x32_bf16(wf, hf, acc2[m], 0, 0, 0);
            }
        }
        LN_T(3, 4, 5, acc2);
        H_STORE_T(acc2);

        // ---------- Layer 3 ----------
        f32x4 acc3[4] = {{0,0,0,0},{0,0,0,0},{0,0,0,0},{0,0,0,0}};
        #pragma unroll
        for (int kb = 0; kb < 2; ++kb) {
            const short8 hf = *reinterpret_cast<const short8*>(
                hwv + cl * 72 + kb * 32 + kg * 8);
            #pragma unroll
            for (int m = 0; m < 4; ++m) {
                const short8 wf = *reinterpret_cast<const short8*>(
                    &wlds[(24 + m * 2 + kb) * 512 + lane * 8]);
                acc3[m] = __builtin_amdgcn_mfma_f32_16x16x32_bf16(wf, hf, acc3[m], 0, 0, 0);
            }
        }
        LN_T(6, 7, 8, acc3);

        // ---------- Layer 4: in-lane dot + kg-reduce + sigmoid ----------
        float p = 0.f;
        #pragma unroll
        for (int m = 0; m < 4; ++m) {
            const float4 w4 = *reinterpret_cast<const float4*>(
                plds + 9 * 64 + m * 16 + kg * 4);
            p = fmaf(acc3[m][0], w4.x, p); p = fmaf(acc3[m][1], w4.y, p);
            p = fmaf(acc3[m][2], w4.z, p); p = fmaf(acc3[m][3], w4.w, p);
        }
        p += __shfl_xor(p, 16); p += __shfl_xor(p, 32);
        if (kg == 0) {
            const int e = e0 + cl;
            if (e < E) {
                const float o = p + b4s;
                out[e] = __builtin_amdgcn_rcpf(1.0f + __expf(-o));
            }
        }
    }
}

__global__ __launch_bounds__(256) void cvt_x_bf16(const float* __restrict__ x,
                                                  unsigned short* __restrict__ xbf,
                                                  int n) {
    const int i = (blockIdx.x * 256 + threadIdx.x) * 8;
    if (i >= n) return;
    const float4 u0 = *reinterpret_cast<const float4*>(x + i);
    const float4 u1 = *reinterpret_cast<const float4*>(x + i + 4);
    uint4 t;
    t.x = pkbf(u0.x, u0.y); t.y = pkbf(u0.z, u0.w);
    t.z = pkbf(u1.x, u1.y); t.w = pkbf(u1.z, u1.w);
    *reinterpret_cast<uint4*>(xbf + i) = t;
}

extern "C" void kernel_launch(void* const* d_in, const int* in_sizes, int n_in,
                              void* d_out, int out_size, void* d_ws, size_t ws_size,
                              hipStream_t stream) {
    const float* x   = (const float*)d_in[0];
    const int*   ei  = (const int*)  d_in[1];
    const float* W1  = (const float*)d_in[2];
    const float* b1  = (const float*)d_in[3];
    const float* g1  = (const float*)d_in[4];
    const float* bt1 = (const float*)d_in[5];
    const float* W2  = (const float*)d_in[6];
    const float* b2  = (const float*)d_in[7];
    const float* g2  = (const float*)d_in[8];
    const float* bt2 = (const float*)d_in[9];
    const float* W3  = (const float*)d_in[10];
    const float* b3  = (const float*)d_in[11];
    const float* g3  = (const float*)d_in[12];
    const float* bt3 = (const float*)d_in[13];
    const float* W4  = (const float*)d_in[14];
    const float* b4  = (const float*)d_in[15];
    float* out = (float*)d_out;

    const int E  = in_sizes[1] / 2;
    const int nX = in_sizes[0];                 // n_nodes * 64

    if (ws_size >= (size_t)nX * 2) {
        unsigned short* xbf = (unsigned short*)d_ws;
        const int grid_c = (nX / 8 + 255) / 256;
        hipLaunchKernelGGL(cvt_x_bf16, dim3(grid_c), dim3(256), 0, stream, x, xbf, nX);
        hipLaunchKernelGGL((edge_mlp_t<true>), dim3(GRID), dim3(BLOCK), 0, stream,
                           (const void*)xbf, ei, W1, b1, g1, bt1, W2, b2, g2, bt2,
                           W3, b3, g3, bt3, W4, b4, out, E);
    } else {
        hipLaunchKernelGGL((edge_mlp_t<false>), dim3(GRID), dim3(BLOCK), 0, stream,
                           (const void*)x, ei, W1, b1, g1, bt1, W2, b2, g2, bt2,
                           W3, b3, g3, bt3, W4, b4, out, E);
    }
}